// Round 1
// baseline (261.194 us; speedup 1.0000x reference)
//
#include <hip/hip_runtime.h>

// VectorCollapseEngine R3: split the fused kernel into pure-streaming passes.
// The 6 affine-in-h layers collapse to h_final = A*h0 + sum_k w_k anchor_k,
// where A, w depend only on 4 per-row scalars {|h|^2, h.a0, h.a1, h.a2}.
// R2 (fused, 259.7us) ran a ~2-3K-cycle serial single-lane recurrence +
// 2 barriers + 24 cross-wave shuffles inside EVERY one of 8192 blocks,
// landing at 6.3x the memory floor. R3 structure:
//   dots  (8193 blocks): stream h0 (128MB), 4 dots/row -> scratch  [mem-bound]
//   recur (32 blocks):   one THREAD per row, 8192 parallel recurrences [~2us]
//   apply (8192 blocks): out = A*h0 + W*anchors (256MB)            [mem-bound]
// Scratch lives in static __device__ arrays -> no assumptions on ws_size.

constexpr int DIM = 4096;
constexpr int BATCH = 8192;
constexpr int NLAYERS = 6;
constexpr int TPB = 256;
constexpr int VPT = DIM / (TPB * 4);  // float4 chunks per thread = 4

constexpr size_t HOUT = (size_t)BATCH * DIM;            // h_final elems
constexpr size_t TRACE = (size_t)NLAYERS * BATCH * 3;   // per-trace elems
constexpr size_t OFF_ALIGN = HOUT;
constexpr size_t OFF_DIV   = HOUT + TRACE;
constexpr size_t OFF_TENS  = HOUT + 2 * TRACE;

// Static device scratch (1MB) — avoids any dependence on ws_size.
__device__ float  g_gram[16];      // [n0,n1,n2, G01,G02,G12, G00,G11,G22]
__device__ float4 g_dots[BATCH];   // {|h|^2, h.a0, h.a1, h.a2} per row
__device__ float4 g_coef[BATCH];   // {A, w0, w1, w2} per row

__device__ __forceinline__ float wave_red(float v) {
#pragma unroll
  for (int off = 32; off > 0; off >>= 1) v += __shfl_down(v, off, 64);
  return v;  // lane 0 holds the wave sum
}

// ---- pass 1: per-row dots; block BATCH computes the anchor Gram ----
__global__ __launch_bounds__(TPB) void dots_kernel(
    const float* __restrict__ h0,
    const float* __restrict__ an0, const float* __restrict__ an1,
    const float* __restrict__ an2) {
  const int tid = threadIdx.x;
  const int b = blockIdx.x;
  const int lane = tid & 63, wv = tid >> 6;
  __shared__ float lds[4][6];

  if (b == BATCH) {
    // ---- anchor Gram / norms (row-independent, one block) ----
    float r[6];
#pragma unroll
    for (int i = 0; i < 6; ++i) r[i] = 0.f;
#pragma unroll
    for (int j = 0; j < VPT; ++j) {
      const int idx = (tid + j * TPB) * 4;
      const float4 x = *(const float4*)(an0 + idx);
      const float4 y = *(const float4*)(an1 + idx);
      const float4 z = *(const float4*)(an2 + idx);
      r[0] += x.x*x.x + x.y*x.y + x.z*x.z + x.w*x.w;
      r[1] += y.x*y.x + y.y*y.y + y.z*y.z + y.w*y.w;
      r[2] += z.x*z.x + z.y*z.y + z.z*z.z + z.w*z.w;
      r[3] += x.x*y.x + x.y*y.y + x.z*y.z + x.w*y.w;
      r[4] += x.x*z.x + x.y*z.y + x.z*z.z + x.w*z.w;
      r[5] += y.x*z.x + y.y*z.y + y.z*z.z + y.w*z.w;
    }
#pragma unroll
    for (int i = 0; i < 6; ++i) r[i] = wave_red(r[i]);
    if (lane == 0) {
#pragma unroll
      for (int i = 0; i < 6; ++i) lds[wv][i] = r[i];
    }
    __syncthreads();
    if (tid == 0) {
#pragma unroll
      for (int i = 0; i < 6; ++i)
        r[i] = lds[0][i] + lds[1][i] + lds[2][i] + lds[3][i];
      const float n0 = fmaxf(sqrtf(r[0]), 1e-12f);
      const float n1 = fmaxf(sqrtf(r[1]), 1e-12f);
      const float n2 = fmaxf(sqrtf(r[2]), 1e-12f);
      g_gram[0] = n0; g_gram[1] = n1; g_gram[2] = n2;
      g_gram[3] = r[3] / (n0 * n1);
      g_gram[4] = r[4] / (n0 * n2);
      g_gram[5] = r[5] / (n1 * n2);
      g_gram[6] = r[0] / (n0 * n0);
      g_gram[7] = r[1] / (n1 * n1);
      g_gram[8] = r[2] / (n2 * n2);
    }
    return;
  }

  // ---- row dots: {|h|^2, h.a0, h.a1, h.a2} ----
  const float* hrow = h0 + (size_t)b * DIM;
  float r[4] = {0.f, 0.f, 0.f, 0.f};
#pragma unroll
  for (int j = 0; j < VPT; ++j) {
    const int idx = (tid + j * TPB) * 4;
    const float4 h = *(const float4*)(hrow + idx);
    const float4 x = *(const float4*)(an0 + idx);
    const float4 y = *(const float4*)(an1 + idx);
    const float4 z = *(const float4*)(an2 + idx);
    r[0] += h.x*h.x + h.y*h.y + h.z*h.z + h.w*h.w;
    r[1] += h.x*x.x + h.y*x.y + h.z*x.z + h.w*x.w;
    r[2] += h.x*y.x + h.y*y.y + h.z*y.z + h.w*y.w;
    r[3] += h.x*z.x + h.y*z.y + h.z*z.z + h.w*z.w;
  }
#pragma unroll
  for (int i = 0; i < 4; ++i) r[i] = wave_red(r[i]);
  if (lane == 0) {
#pragma unroll
    for (int i = 0; i < 4; ++i) lds[wv][i] = r[i];
  }
  __syncthreads();
  if (tid == 0) {
    g_dots[b] = make_float4(lds[0][0] + lds[1][0] + lds[2][0] + lds[3][0],
                            lds[0][1] + lds[1][1] + lds[2][1] + lds[3][1],
                            lds[0][2] + lds[1][2] + lds[2][2] + lds[3][2],
                            lds[0][3] + lds[1][3] + lds[2][3] + lds[3][3]);
  }
}

// ---- pass 2: one THREAD per row — 8192 fully parallel recurrences ----
__global__ __launch_bounds__(TPB) void recur_kernel(float* __restrict__ out) {
  const int b = blockIdx.x * TPB + threadIdx.x;  // row id, 0..8191
  const float4 dt = g_dots[b];

  const float n0 = g_gram[0], n1 = g_gram[1], n2 = g_gram[2];
  float G[3][3];
  G[0][1] = G[1][0] = g_gram[3];
  G[0][2] = G[2][0] = g_gram[4];
  G[1][2] = G[2][1] = g_gram[5];
  G[0][0] = g_gram[6]; G[1][1] = g_gram[7]; G[2][2] = g_gram[8];

  const float str[3] = {0.1f, 0.1f, 0.05f};
  float s = dt.x;
  float d[3] = {dt.y / n0, dt.z / n1, dt.w / n2};
  float A = 1.f;
  float B[3] = {0.f, 0.f, 0.f};

#pragma unroll
  for (int l = 0; l < NLAYERS; ++l) {
    const float hn = fmaxf(sqrtf(s), 1e-12f);
    float al[3], dv[3], c[3];
#pragma unroll
    for (int k = 0; k < 3; ++k) {
      al[k] = d[k] / hn;
      dv[k] = 1.f - al[k];
      const float rr = fmaxf(sqrtf(s - 2.f * d[k] + G[k][k]), 1e-12f);
      c[k] = str[k] * dv[k] / rr;
    }
#pragma unroll
    for (int k = 0; k < 3; ++k) {
      const size_t o = (size_t)l * (BATCH * 3) + (size_t)b * 3 + k;
      out[OFF_ALIGN + o] = al[k];
      out[OFF_DIV + o]   = dv[k];
      out[OFF_TENS + o]  = fmaxf(dv[k], 0.f);
    }
    const float a = 1.f - (c[0] + c[1] + c[2]);
    float dn[3];
#pragma unroll
    for (int j = 0; j < 3; ++j)
      dn[j] = a * d[j] + c[0] * G[0][j] + c[1] * G[1][j] + c[2] * G[2][j];
    float sn = a * a * s + 2.f * a * (c[0]*d[0] + c[1]*d[1] + c[2]*d[2]);
#pragma unroll
    for (int k = 0; k < 3; ++k)
#pragma unroll
      for (int j = 0; j < 3; ++j) sn += c[k] * c[j] * G[k][j];
    A = a * A;
#pragma unroll
    for (int j = 0; j < 3; ++j) B[j] = a * B[j] + c[j];
    s = sn;
#pragma unroll
    for (int j = 0; j < 3; ++j) d[j] = dn[j];
    const float hn2 = sqrtf(s);
    if (hn2 > 10.0f) {
      const float sc = 10.0f / (hn2 + 1e-8f);
      A *= sc;
#pragma unroll
      for (int j = 0; j < 3; ++j) { B[j] *= sc; d[j] *= sc; }
      s *= sc * sc;
    }
  }
  g_coef[b] = make_float4(A, B[0] / n0, B[1] / n1, B[2] / n2);
}

// ---- pass 3: out = A*h0 + w0*a0 + w1*a1 + w2*a2 (pure stream) ----
__global__ __launch_bounds__(TPB) void apply_kernel(
    const float* __restrict__ h0,
    const float* __restrict__ an0, const float* __restrict__ an1,
    const float* __restrict__ an2, float* __restrict__ out) {
  const int b = blockIdx.x;
  const int tid = threadIdx.x;
  const float4 cf = g_coef[b];  // uniform per block -> scalar load
  const float* hrow = h0 + (size_t)b * DIM;
  float* orow = out + (size_t)b * DIM;
#pragma unroll
  for (int j = 0; j < VPT; ++j) {
    const int idx = (tid + j * TPB) * 4;
    const float4 h = *(const float4*)(hrow + idx);
    const float4 x = *(const float4*)(an0 + idx);
    const float4 y = *(const float4*)(an1 + idx);
    const float4 z = *(const float4*)(an2 + idx);
    float4 o;
    o.x = cf.x * h.x + cf.y * x.x + cf.z * y.x + cf.w * z.x;
    o.y = cf.x * h.y + cf.y * x.y + cf.z * y.y + cf.w * z.y;
    o.z = cf.x * h.z + cf.y * x.z + cf.z * y.z + cf.w * z.z;
    o.w = cf.x * h.w + cf.y * x.w + cf.z * y.w + cf.w * z.w;
    *(float4*)(orow + idx) = o;
  }
}

extern "C" void kernel_launch(void* const* d_in, const int* in_sizes, int n_in,
                              void* d_out, int out_size, void* d_ws, size_t ws_size,
                              hipStream_t stream) {
  const float* h0  = (const float*)d_in[0];
  const float* an0 = (const float*)d_in[1];
  const float* an1 = (const float*)d_in[2];
  const float* an2 = (const float*)d_in[3];
  float* out = (float*)d_out;
  (void)d_ws; (void)ws_size;
  dots_kernel<<<BATCH + 1, TPB, 0, stream>>>(h0, an0, an1, an2);
  recur_kernel<<<BATCH / TPB, TPB, 0, stream>>>(out);
  apply_kernel<<<BATCH, TPB, 0, stream>>>(h0, an0, an1, an2, out);
}